// Round 4
// baseline (71.819 us; speedup 1.0000x reference)
//
#include <hip/hip_runtime.h>
#include <math.h>

#define NB   1024
#define CH   60
#define SW   288
#define F1C  8
#define FD   16   // F1*D
#define F2C  16
#define KLEN 64
#define NCLS 4
#define PWID 72
#define NV   9
#define FEAT 144
#define NTHR 320

#define XR_STRIDE 356   // mult of 4 (b128-aligned rows)
#define PH_STRIDE 76    // mult of 4
#define W1_STRIDE 68    // mult of 4

__device__ __forceinline__ float elu1(float v) {
    return v > 0.f ? v : __expf(v) - 1.f;   // native v_exp_f32
}

__device__ __forceinline__ unsigned short f2bf(float f) {   // RNE f32 -> bf16
    unsigned int u = __float_as_uint(f);
    u = (u + 0x7fffu + ((u >> 16) & 1u)) >> 16;
    return (unsigned short)u;
}

// ---------------- kernel A: xr[b][f][w] = sum_ch dw[f][ch] * x[b][ch][w] ----
// streaming, no barriers; 2 width-elements per thread; bf16 output.
__global__ __launch_bounds__(256, 4) void eegnet_chreduce(
    const float* __restrict__ x, const float* __restrict__ dw_w,
    unsigned int* __restrict__ xr,        // bf16 pairs, [1024][16][144] uints
    float* __restrict__ zero_ws,          // sums(576)+cnt(4) to zero
    float* __restrict__ cl)               // loss accumulator to zero
{
    const int g = blockIdx.x * 256 + threadIdx.x;    // 0..147455
    if (blockIdx.x == 0) {
        for (int i = threadIdx.x; i < 580; i += 256) zero_ws[i] = 0.f;
        if (threadIdx.x == 0) cl[0] = 0.f;
    }
    const int b = g / 144;
    const int w2 = g - b * 144;
    const float2* xb2 = (const float2*)(x + (size_t)b * (CH * SW)) + w2;

    float2 acc[FD];
    #pragma unroll
    for (int f = 0; f < FD; ++f) { acc[f].x = 0.f; acc[f].y = 0.f; }

    float2 xa[12];
    #pragma unroll
    for (int j = 0; j < 12; ++j) xa[j] = xb2[j * 144];
    #pragma unroll
    for (int c0 = 0; c0 < CH; c0 += 12) {
        float2 xn[12];
        if (c0 + 12 < CH) {
            #pragma unroll
            for (int j = 0; j < 12; ++j) xn[j] = xb2[(c0 + 12 + j) * 144];
        }
        #pragma unroll
        for (int j = 0; j < 12; ++j) {
            const float2 v = xa[j];
            #pragma unroll
            for (int f = 0; f < FD; ++f) {
                const float wv = dw_w[f * CH + c0 + j];   // wave-uniform -> s_load
                acc[f].x = fmaf(wv, v.x, acc[f].x);
                acc[f].y = fmaf(wv, v.y, acc[f].y);
            }
        }
        if (c0 + 12 < CH) {
            #pragma unroll
            for (int j = 0; j < 12; ++j) xa[j] = xn[j];
        }
    }
    const size_t base = (size_t)b * (FD * 144) + w2;
    #pragma unroll
    for (int f = 0; f < FD; ++f) {
        const unsigned int h0 = f2bf(acc[f].x), h1 = f2bf(acc[f].y);
        xr[base + f * 144] = h0 | (h1 << 16);
    }
}

// ---------------- kernel B: per-batch conv+bn2+elu+pool4+pointwise+head ------
__global__ __launch_bounds__(NTHR, 4) void eegnet_head(
    const unsigned int* __restrict__ xr, const int* __restrict__ y,
    const float* __restrict__ conv1_w,
    const float* __restrict__ bn1_g, const float* __restrict__ bn1_b,
    const float* __restrict__ bn1_m, const float* __restrict__ bn1_v,
    const float* __restrict__ dw_w,
    const float* __restrict__ bn2_g, const float* __restrict__ bn2_b,
    const float* __restrict__ bn2_m, const float* __restrict__ bn2_v,
    const float* __restrict__ pw_w,
    const float* __restrict__ bn3_g, const float* __restrict__ bn3_b,
    const float* __restrict__ bn3_m, const float* __restrict__ bn3_v,
    const float* __restrict__ fc_w, const float* __restrict__ fc_b,
    float* __restrict__ probs_out, float* __restrict__ feat_out,
    float* __restrict__ sums_out, int* __restrict__ cnt_out)
{
    __shared__ __align__(16) float s_xr[FD * XR_STRIDE];
    __shared__ __align__(16) float s_w1[F1C * W1_STRIDE];
    __shared__ __align__(16) float s_ph[FD * PH_STRIDE];
    __shared__ float s_pwT[FD * F2C];
    __shared__ float s_feat[FEAT];
    __shared__ float s_A[FD], s_Cb[FD], s_a3[F2C], s_c3[F2C];

    const int tid = threadIdx.x;
    const int b = blockIdx.x;

    // ---- stage: weights, xr tile (bf16 -> f32), pads, BN folds ----
    if (tid == 0) atomicAdd(&cnt_out[y[b]], 1);
    for (int i = tid; i < F1C * KLEN; i += NTHR)
        s_w1[(i >> 6) * W1_STRIDE + (i & 63)] = conv1_w[i];
    for (int i = tid; i < F2C * FD; i += NTHR)
        s_pwT[(i & 15) * F2C + (i >> 4)] = pw_w[i];
    for (int i = tid; i < FD * 68; i += NTHR) {     // pads: words [0,32) and [320,356)
        int f = i / 68, p = i % 68;
        int wp = (p < 32) ? p : (288 + p);
        s_xr[f * XR_STRIDE + wp] = 0.f;
    }
    // xr[b]: 16x288 bf16 = 576 uint4 (8 bf16 each)
    {
        const uint4* xrb = (const uint4*)(xr + (size_t)b * (FD * 144));
        for (int i = tid; i < 576; i += NTHR) {
            const int f = i / 36;
            const int k = i - f * 36;                // 8-wide group
            const uint4 v = xrb[i];
            float* dst = &s_xr[f * XR_STRIDE + 32 + 8 * k];
            float4 lo, hi;
            lo.x = __uint_as_float(v.x << 16); lo.y = __uint_as_float(v.x & 0xffff0000u);
            lo.z = __uint_as_float(v.y << 16); lo.w = __uint_as_float(v.y & 0xffff0000u);
            hi.x = __uint_as_float(v.z << 16); hi.y = __uint_as_float(v.z & 0xffff0000u);
            hi.z = __uint_as_float(v.w << 16); hi.w = __uint_as_float(v.w & 0xffff0000u);
            *(float4*)dst = lo;
            *(float4*)(dst + 4) = hi;
        }
    }
    if (tid < FD) {
        const int f = tid, f1 = f >> 1;
        const float inv1 = bn1_g[f1] / sqrtf(bn1_v[f1] + 1e-3f);
        const float c1 = bn1_b[f1] - bn1_m[f1] * inv1;
        const float inv2 = bn2_g[f] / sqrtf(bn2_v[f] + 1e-3f);
        const float c2 = bn2_b[f] - bn2_m[f] * inv2;
        float sdw = 0.f;
        for (int ch = 0; ch < CH; ++ch) sdw += dw_w[f * CH + ch];
        s_A[f] = inv2 * inv1;
        s_Cb[f] = inv2 * c1 * sdw + c2;
        const float inv3 = bn3_g[f] / sqrtf(bn3_v[f] + 1e-3f);
        s_a3[f] = inv3;
        s_c3[f] = bn3_b[f] - bn3_m[f] * inv3;
    }
    __syncthreads();

    // ---- phase 2: K=64 conv + bn2 + elu + pool4, 16 conv outputs/thread ----
    if (tid < 288) {
        const int f = tid & 15;
        const int q = tid >> 4;                   // 0..17
        const float4* xp = (const float4*)&s_xr[f * XR_STRIDE + 16 * q];
        const float4* wp = (const float4*)&s_w1[(f >> 1) * W1_STRIDE];
        float cw[20];
        #pragma unroll
        for (int i = 0; i < 4; ++i) {
            const float4 t = xp[i];
            cw[4*i] = t.x; cw[4*i+1] = t.y; cw[4*i+2] = t.z; cw[4*i+3] = t.w;
        }
        float bb[16];
        #pragma unroll
        for (int j = 0; j < 16; ++j) bb[j] = 0.f;
        #pragma unroll
        for (int m = 0; m < 16; ++m) {
            {
                const float4 t = xp[m + 4];
                const int s = (4 * (m + 4)) % 20;     // mult of 4, never wraps mid-vec
                cw[s] = t.x; cw[s+1] = t.y; cw[s+2] = t.z; cw[s+3] = t.w;
            }
            const float4 wv = wp[m];
            #pragma unroll
            for (int j = 0; j < 16; ++j) {
                bb[j] = fmaf(wv.x, cw[(4*m + j    ) % 20], bb[j]);
                bb[j] = fmaf(wv.y, cw[(4*m + j + 1) % 20], bb[j]);
                bb[j] = fmaf(wv.z, cw[(4*m + j + 2) % 20], bb[j]);
                bb[j] = fmaf(wv.w, cw[(4*m + j + 3) % 20], bb[j]);
            }
        }
        const float Af = s_A[f], Cf = s_Cb[f];
        float e[16];
        #pragma unroll
        for (int j = 0; j < 16; ++j) e[j] = elu1(fmaf(Af, bb[j], Cf));
        float4 ph;
        ph.x = (e[0]  + e[1]  + e[2]  + e[3])  * 0.25f;
        ph.y = (e[4]  + e[5]  + e[6]  + e[7])  * 0.25f;
        ph.z = (e[8]  + e[9]  + e[10] + e[11]) * 0.25f;
        ph.w = (e[12] + e[13] + e[14] + e[15]) * 0.25f;
        *(float4*)&s_ph[f * PH_STRIDE + 4 * q] = ph;
    }
    __syncthreads();

    // ---- phase 3: pointwise 16x16 + bn3 + elu + pool8 -> feat[144] ----
    if (tid < FEAT) {
        const int f2 = tid / NV;
        const int v = tid - f2 * NV;
        float su[8];
        #pragma unroll
        for (int k = 0; k < 8; ++k) su[k] = 0.f;
        #pragma unroll
        for (int f = 0; f < FD; ++f) {
            const float w = s_pwT[f * F2C + f2];
            const float4 p0 = *(const float4*)&s_ph[f * PH_STRIDE + 8 * v];
            const float4 p1 = *(const float4*)&s_ph[f * PH_STRIDE + 8 * v + 4];
            su[0] = fmaf(w, p0.x, su[0]); su[1] = fmaf(w, p0.y, su[1]);
            su[2] = fmaf(w, p0.z, su[2]); su[3] = fmaf(w, p0.w, su[3]);
            su[4] = fmaf(w, p1.x, su[4]); su[5] = fmaf(w, p1.y, su[5]);
            su[6] = fmaf(w, p1.z, su[6]); su[7] = fmaf(w, p1.w, su[7]);
        }
        const float a3f = s_a3[f2], c3f = s_c3[f2];
        float acc = 0.f;
        #pragma unroll
        for (int k = 0; k < 8; ++k) acc += elu1(fmaf(a3f, su[k], c3f));
        const float ft = acc * 0.125f;
        s_feat[tid] = ft;
        feat_out[(size_t)b * FEAT + tid] = ft;
        atomicAdd(&sums_out[y[b] * FEAT + tid], ft);
    }
    __syncthreads();

    // ---- phase 4: logits + softmax (wave 0; fc_w from L2) ----
    if (tid < 64) {
        float lg0 = 0.f, lg1 = 0.f, lg2 = 0.f, lg3 = 0.f;
        for (int j = tid; j < FEAT; j += 64) {
            const float fv = s_feat[j];
            lg0 = fmaf(fv, fc_w[0 * FEAT + j], lg0);
            lg1 = fmaf(fv, fc_w[1 * FEAT + j], lg1);
            lg2 = fmaf(fv, fc_w[2 * FEAT + j], lg2);
            lg3 = fmaf(fv, fc_w[3 * FEAT + j], lg3);
        }
        #pragma unroll
        for (int off = 32; off > 0; off >>= 1) {
            lg0 += __shfl_down(lg0, off, 64);
            lg1 += __shfl_down(lg1, off, 64);
            lg2 += __shfl_down(lg2, off, 64);
            lg3 += __shfl_down(lg3, off, 64);
        }
        if (tid == 0) {
            lg0 += fc_b[0]; lg1 += fc_b[1]; lg2 += fc_b[2]; lg3 += fc_b[3];
            const float m = fmaxf(fmaxf(lg0, lg1), fmaxf(lg2, lg3));
            const float e0 = __expf(lg0 - m), e1 = __expf(lg1 - m);
            const float e2 = __expf(lg2 - m), e3 = __expf(lg3 - m);
            const float inv = 1.f / (e0 + e1 + e2 + e3);
            float* po = probs_out + (size_t)b * NCLS;
            po[0] = e0 * inv; po[1] = e1 * inv; po[2] = e2 * inv; po[3] = e3 * inv;
        }
    }
}

// ---------------- kernel C: centroid distances ------------------------------
__global__ __launch_bounds__(64) void eegnet_dist(
    const float* __restrict__ feat, const int* __restrict__ y,
    const float* __restrict__ sums, const int* __restrict__ cnt,
    float* __restrict__ cl_out)
{
    __shared__ float s_cent[NCLS * FEAT];
    const int tid = threadIdx.x;
    for (int i = tid; i < NCLS * FEAT; i += 64)
        s_cent[i] = sums[i] / fmaxf((float)cnt[i / FEAT], 1.0f);
    __syncthreads();

    const int s = blockIdx.x * 64 + tid;
    const float* fp = feat + (size_t)s * FEAT;
    const float* cp = &s_cent[y[s] * FEAT];
    float acc = 0.f;
    #pragma unroll
    for (int j = 0; j < FEAT; j += 4) {
        const float4 fv = *reinterpret_cast<const float4*>(fp + j);
        float d;
        d = fv.x - cp[j + 0] + 1e-6f; acc = fmaf(d, d, acc);
        d = fv.y - cp[j + 1] + 1e-6f; acc = fmaf(d, d, acc);
        d = fv.z - cp[j + 2] + 1e-6f; acc = fmaf(d, d, acc);
        d = fv.w - cp[j + 3] + 1e-6f; acc = fmaf(d, d, acc);
    }
    float dist = sqrtf(acc);
    #pragma unroll
    for (int off = 32; off > 0; off >>= 1) dist += __shfl_down(dist, off, 64);
    if (tid == 0) atomicAdd(cl_out, dist * (1.0f / 1024.0f));
}

extern "C" void kernel_launch(void* const* d_in, const int* in_sizes, int n_in,
                              void* d_out, int out_size, void* d_ws, size_t ws_size,
                              hipStream_t stream) {
    const float* x       = (const float*)d_in[0];
    const int*   y       = (const int*)d_in[1];
    const float* conv1_w = (const float*)d_in[2];
    const float* bn1_g   = (const float*)d_in[3];
    const float* bn1_b   = (const float*)d_in[4];
    const float* bn1_m   = (const float*)d_in[5];
    const float* bn1_v   = (const float*)d_in[6];
    const float* dw_w    = (const float*)d_in[7];
    const float* bn2_g   = (const float*)d_in[8];
    const float* bn2_b   = (const float*)d_in[9];
    const float* bn2_m   = (const float*)d_in[10];
    const float* bn2_v   = (const float*)d_in[11];
    const float* pw_w    = (const float*)d_in[12];
    const float* bn3_g   = (const float*)d_in[13];
    const float* bn3_b   = (const float*)d_in[14];
    const float* bn3_m   = (const float*)d_in[15];
    const float* bn3_v   = (const float*)d_in[16];
    const float* fc_w    = (const float*)d_in[17];
    const float* fc_b    = (const float*)d_in[18];

    float* out   = (float*)d_out;
    float* probs = out;                              // [1024*4]
    float* cl    = out + 4096;                       // [1]
    float* sums  = (float*)d_ws;                     // 576 floats
    int*   cnt   = (int*)((char*)d_ws + 2304);       // 4 ints
    float* feat  = (float*)((char*)d_ws + 2560);     // 1024*144 f32
    unsigned int* xrbuf = (unsigned int*)((char*)d_ws + 2560 + 589824); // bf16 pairs, 9.44 MB

    eegnet_chreduce<<<576, 256, 0, stream>>>(x, dw_w, xrbuf, sums, cl);
    eegnet_head<<<NB, NTHR, 0, stream>>>(
        xrbuf, y, conv1_w, bn1_g, bn1_b, bn1_m, bn1_v,
        dw_w, bn2_g, bn2_b, bn2_m, bn2_v,
        pw_w, bn3_g, bn3_b, bn3_m, bn3_v,
        fc_w, fc_b, probs, feat, sums, cnt);
    eegnet_dist<<<16, 64, 0, stream>>>(feat, y, sums, cnt, cl);
}

// Round 5
// 51.153 us; speedup vs baseline: 1.4040x; 1.4040x over previous
//
#include <hip/hip_runtime.h>
#include <math.h>

#define NB   1024
#define CH   60
#define SW   288
#define F1C  8
#define FD   16   // F1*D
#define F2C  16
#define KLEN 64
#define NCLS 4
#define PWID 72
#define NV   9
#define FEAT 144
#define NTHR 320
#define ACH  30   // channels per thread in kernel A (2-way split)

#define XR_STRIDE 356   // mult of 4 (b128-aligned rows)
#define PH_STRIDE 76    // mult of 4
#define W1_STRIDE 68    // mult of 4

__device__ __forceinline__ float elu1(float v) {
    return v > 0.f ? v : __expf(v) - 1.f;   // native v_exp_f32
}

__device__ __forceinline__ unsigned short f2bf(float f) {   // RNE f32 -> bf16
    unsigned int u = __float_as_uint(f);
    u = (u + 0x7fffu + ((u >> 16) & 1u)) >> 16;
    return (unsigned short)u;
}

// ---------------- kernel A: xr[b][f][w] = sum_ch dw[f][ch] * x[b][ch][w] ----
// one width element per thread; channel dim split across partner waves
// (h=0/1), combined through LDS. v[30]+acc[16] ~ 56 VGPR -> full 30-deep
// load prefetch INSIDE the 64-reg/8-wave bucket (round-4 failure mode fixed).
__global__ __launch_bounds__(256, 8) void eegnet_chreduce(
    const float* __restrict__ x, const float* __restrict__ dw_w,
    unsigned short* __restrict__ xr,      // bf16 [1024][16][288]
    float* __restrict__ zero_ws,          // sums(576)+cnt(4) to zero
    float* __restrict__ cl)               // loss accumulator to zero
{
    __shared__ float s_part[2][FD][65];   // h=1 partials; stride 65 -> conflict-free
    const int tid = threadIdx.x;
    if (blockIdx.x == 0) {
        for (int i = tid; i < 580; i += 256) zero_ws[i] = 0.f;
        if (tid == 0) cl[0] = 0.f;
    }
    const int wv   = tid >> 6;            // wave in block: 0..3
    const int lane = tid & 63;
    const int h  = __builtin_amdgcn_readfirstlane(wv & 1);   // channel half (SGPR)
    const int es = wv >> 1;               // e-slot in block: 0/1
    const int e  = blockIdx.x * 2 + es;   // 0..4607
    const int wflat = e * 64 + lane;      // 0..294911 over [b][w]
    const int b = wflat / SW;             // const-divisor -> magic mul
    const int w = wflat - b * SW;

    const float* xp = x + (size_t)b * (CH * SW) + (size_t)(h * ACH) * SW + w;
    float v[ACH];
    #pragma unroll
    for (int j = 0; j < ACH; ++j) v[j] = xp[j * SW];   // 30 loads in flight

    float acc[FD];
    #pragma unroll
    for (int f = 0; f < FD; ++f) acc[f] = 0.f;
    #pragma unroll
    for (int j = 0; j < ACH; ++j) {
        const float xv = v[j];
        #pragma unroll
        for (int f = 0; f < FD; ++f)
            acc[f] = fmaf(dw_w[f * CH + h * ACH + j], xv, acc[f]);  // s_load
    }

    if (h == 1) {
        #pragma unroll
        for (int f = 0; f < FD; ++f) s_part[es][f][lane] = acc[f];
    }
    __syncthreads();
    if (h == 0) {
        const size_t base = (size_t)b * (FD * SW) + w;
        #pragma unroll
        for (int f = 0; f < FD; ++f)
            xr[base + f * SW] = f2bf(acc[f] + s_part[es][f][lane]);
    }
}

// ---------------- kernel B: per-batch conv+bn2+elu+pool4+pointwise+head ------
__global__ __launch_bounds__(NTHR, 4) void eegnet_head(
    const unsigned int* __restrict__ xr, const int* __restrict__ y,
    const float* __restrict__ conv1_w,
    const float* __restrict__ bn1_g, const float* __restrict__ bn1_b,
    const float* __restrict__ bn1_m, const float* __restrict__ bn1_v,
    const float* __restrict__ dw_w,
    const float* __restrict__ bn2_g, const float* __restrict__ bn2_b,
    const float* __restrict__ bn2_m, const float* __restrict__ bn2_v,
    const float* __restrict__ pw_w,
    const float* __restrict__ bn3_g, const float* __restrict__ bn3_b,
    const float* __restrict__ bn3_m, const float* __restrict__ bn3_v,
    const float* __restrict__ fc_w, const float* __restrict__ fc_b,
    float* __restrict__ probs_out, float* __restrict__ feat_out,
    float* __restrict__ sums_out, int* __restrict__ cnt_out)
{
    __shared__ __align__(16) float s_xr[FD * XR_STRIDE];
    __shared__ __align__(16) float s_w1[F1C * W1_STRIDE];
    __shared__ __align__(16) float s_ph[FD * PH_STRIDE];
    __shared__ float s_pwT[FD * F2C];
    __shared__ float s_feat[FEAT];
    __shared__ float s_A[FD], s_Cb[FD], s_a3[F2C], s_c3[F2C];

    const int tid = threadIdx.x;
    const int b = blockIdx.x;

    // ---- stage: weights, xr tile (bf16 -> f32), pads, BN folds ----
    if (tid == 0) atomicAdd(&cnt_out[y[b]], 1);
    for (int i = tid; i < F1C * KLEN; i += NTHR)
        s_w1[(i >> 6) * W1_STRIDE + (i & 63)] = conv1_w[i];
    for (int i = tid; i < F2C * FD; i += NTHR)
        s_pwT[(i & 15) * F2C + (i >> 4)] = pw_w[i];
    for (int i = tid; i < FD * 68; i += NTHR) {     // pads: words [0,32) and [320,356)
        int f = i / 68, p = i % 68;
        int wp = (p < 32) ? p : (288 + p);
        s_xr[f * XR_STRIDE + wp] = 0.f;
    }
    // xr[b]: 16x288 bf16 = 576 uint4 (8 bf16 each)
    {
        const uint4* xrb = (const uint4*)(xr + (size_t)b * (FD * 144));
        for (int i = tid; i < 576; i += NTHR) {
            const int f = i / 36;
            const int k = i - f * 36;                // 8-wide group
            const uint4 v = xrb[i];
            float* dst = &s_xr[f * XR_STRIDE + 32 + 8 * k];
            float4 lo, hi;
            lo.x = __uint_as_float(v.x << 16); lo.y = __uint_as_float(v.x & 0xffff0000u);
            lo.z = __uint_as_float(v.y << 16); lo.w = __uint_as_float(v.y & 0xffff0000u);
            hi.x = __uint_as_float(v.z << 16); hi.y = __uint_as_float(v.z & 0xffff0000u);
            hi.z = __uint_as_float(v.w << 16); hi.w = __uint_as_float(v.w & 0xffff0000u);
            *(float4*)dst = lo;
            *(float4*)(dst + 4) = hi;
        }
    }
    if (tid < FD) {
        const int f = tid, f1 = f >> 1;
        const float inv1 = bn1_g[f1] / sqrtf(bn1_v[f1] + 1e-3f);
        const float c1 = bn1_b[f1] - bn1_m[f1] * inv1;
        const float inv2 = bn2_g[f] / sqrtf(bn2_v[f] + 1e-3f);
        const float c2 = bn2_b[f] - bn2_m[f] * inv2;
        float sdw = 0.f;
        for (int ch = 0; ch < CH; ++ch) sdw += dw_w[f * CH + ch];
        s_A[f] = inv2 * inv1;
        s_Cb[f] = inv2 * c1 * sdw + c2;
        const float inv3 = bn3_g[f] / sqrtf(bn3_v[f] + 1e-3f);
        s_a3[f] = inv3;
        s_c3[f] = bn3_b[f] - bn3_m[f] * inv3;
    }
    __syncthreads();

    // ---- phase 2: K=64 conv + bn2 + elu + pool4, 16 conv outputs/thread ----
    if (tid < 288) {
        const int f = tid & 15;
        const int q = tid >> 4;                   // 0..17
        const float4* xp = (const float4*)&s_xr[f * XR_STRIDE + 16 * q];
        const float4* wp = (const float4*)&s_w1[(f >> 1) * W1_STRIDE];
        float cw[20];
        #pragma unroll
        for (int i = 0; i < 4; ++i) {
            const float4 t = xp[i];
            cw[4*i] = t.x; cw[4*i+1] = t.y; cw[4*i+2] = t.z; cw[4*i+3] = t.w;
        }
        float bb[16];
        #pragma unroll
        for (int j = 0; j < 16; ++j) bb[j] = 0.f;
        #pragma unroll
        for (int m = 0; m < 16; ++m) {
            {
                const float4 t = xp[m + 4];
                const int s = (4 * (m + 4)) % 20;     // mult of 4, never wraps mid-vec
                cw[s] = t.x; cw[s+1] = t.y; cw[s+2] = t.z; cw[s+3] = t.w;
            }
            const float4 wv = wp[m];
            #pragma unroll
            for (int j = 0; j < 16; ++j) {
                bb[j] = fmaf(wv.x, cw[(4*m + j    ) % 20], bb[j]);
                bb[j] = fmaf(wv.y, cw[(4*m + j + 1) % 20], bb[j]);
                bb[j] = fmaf(wv.z, cw[(4*m + j + 2) % 20], bb[j]);
                bb[j] = fmaf(wv.w, cw[(4*m + j + 3) % 20], bb[j]);
            }
        }
        const float Af = s_A[f], Cf = s_Cb[f];
        float e[16];
        #pragma unroll
        for (int j = 0; j < 16; ++j) e[j] = elu1(fmaf(Af, bb[j], Cf));
        float4 ph;
        ph.x = (e[0]  + e[1]  + e[2]  + e[3])  * 0.25f;
        ph.y = (e[4]  + e[5]  + e[6]  + e[7])  * 0.25f;
        ph.z = (e[8]  + e[9]  + e[10] + e[11]) * 0.25f;
        ph.w = (e[12] + e[13] + e[14] + e[15]) * 0.25f;
        *(float4*)&s_ph[f * PH_STRIDE + 4 * q] = ph;
    }
    __syncthreads();

    // ---- phase 3: pointwise 16x16 + bn3 + elu + pool8 -> feat[144] ----
    if (tid < FEAT) {
        const int f2 = tid / NV;
        const int v = tid - f2 * NV;
        float su[8];
        #pragma unroll
        for (int k = 0; k < 8; ++k) su[k] = 0.f;
        #pragma unroll
        for (int f = 0; f < FD; ++f) {
            const float w = s_pwT[f * F2C + f2];
            const float4 p0 = *(const float4*)&s_ph[f * PH_STRIDE + 8 * v];
            const float4 p1 = *(const float4*)&s_ph[f * PH_STRIDE + 8 * v + 4];
            su[0] = fmaf(w, p0.x, su[0]); su[1] = fmaf(w, p0.y, su[1]);
            su[2] = fmaf(w, p0.z, su[2]); su[3] = fmaf(w, p0.w, su[3]);
            su[4] = fmaf(w, p1.x, su[4]); su[5] = fmaf(w, p1.y, su[5]);
            su[6] = fmaf(w, p1.z, su[6]); su[7] = fmaf(w, p1.w, su[7]);
        }
        const float a3f = s_a3[f2], c3f = s_c3[f2];
        float acc = 0.f;
        #pragma unroll
        for (int k = 0; k < 8; ++k) acc += elu1(fmaf(a3f, su[k], c3f));
        const float ft = acc * 0.125f;
        s_feat[tid] = ft;
        feat_out[(size_t)b * FEAT + tid] = ft;
        atomicAdd(&sums_out[y[b] * FEAT + tid], ft);
    }
    __syncthreads();

    // ---- phase 4: logits + softmax (wave 0; fc_w from L2) ----
    if (tid < 64) {
        float lg0 = 0.f, lg1 = 0.f, lg2 = 0.f, lg3 = 0.f;
        for (int j = tid; j < FEAT; j += 64) {
            const float fv = s_feat[j];
            lg0 = fmaf(fv, fc_w[0 * FEAT + j], lg0);
            lg1 = fmaf(fv, fc_w[1 * FEAT + j], lg1);
            lg2 = fmaf(fv, fc_w[2 * FEAT + j], lg2);
            lg3 = fmaf(fv, fc_w[3 * FEAT + j], lg3);
        }
        #pragma unroll
        for (int off = 32; off > 0; off >>= 1) {
            lg0 += __shfl_down(lg0, off, 64);
            lg1 += __shfl_down(lg1, off, 64);
            lg2 += __shfl_down(lg2, off, 64);
            lg3 += __shfl_down(lg3, off, 64);
        }
        if (tid == 0) {
            lg0 += fc_b[0]; lg1 += fc_b[1]; lg2 += fc_b[2]; lg3 += fc_b[3];
            const float m = fmaxf(fmaxf(lg0, lg1), fmaxf(lg2, lg3));
            const float e0 = __expf(lg0 - m), e1 = __expf(lg1 - m);
            const float e2 = __expf(lg2 - m), e3 = __expf(lg3 - m);
            const float inv = 1.f / (e0 + e1 + e2 + e3);
            float* po = probs_out + (size_t)b * NCLS;
            po[0] = e0 * inv; po[1] = e1 * inv; po[2] = e2 * inv; po[3] = e3 * inv;
        }
    }
}

// ---------------- kernel C: centroid distances ------------------------------
__global__ __launch_bounds__(64) void eegnet_dist(
    const float* __restrict__ feat, const int* __restrict__ y,
    const float* __restrict__ sums, const int* __restrict__ cnt,
    float* __restrict__ cl_out)
{
    __shared__ float s_cent[NCLS * FEAT];
    const int tid = threadIdx.x;
    for (int i = tid; i < NCLS * FEAT; i += 64)
        s_cent[i] = sums[i] / fmaxf((float)cnt[i / FEAT], 1.0f);
    __syncthreads();

    const int s = blockIdx.x * 64 + tid;
    const float* fp = feat + (size_t)s * FEAT;
    const float* cp = &s_cent[y[s] * FEAT];
    float acc = 0.f;
    #pragma unroll
    for (int j = 0; j < FEAT; j += 4) {
        const float4 fv = *reinterpret_cast<const float4*>(fp + j);
        float d;
        d = fv.x - cp[j + 0] + 1e-6f; acc = fmaf(d, d, acc);
        d = fv.y - cp[j + 1] + 1e-6f; acc = fmaf(d, d, acc);
        d = fv.z - cp[j + 2] + 1e-6f; acc = fmaf(d, d, acc);
        d = fv.w - cp[j + 3] + 1e-6f; acc = fmaf(d, d, acc);
    }
    float dist = sqrtf(acc);
    #pragma unroll
    for (int off = 32; off > 0; off >>= 1) dist += __shfl_down(dist, off, 64);
    if (tid == 0) atomicAdd(cl_out, dist * (1.0f / 1024.0f));
}

extern "C" void kernel_launch(void* const* d_in, const int* in_sizes, int n_in,
                              void* d_out, int out_size, void* d_ws, size_t ws_size,
                              hipStream_t stream) {
    const float* x       = (const float*)d_in[0];
    const int*   y       = (const int*)d_in[1];
    const float* conv1_w = (const float*)d_in[2];
    const float* bn1_g   = (const float*)d_in[3];
    const float* bn1_b   = (const float*)d_in[4];
    const float* bn1_m   = (const float*)d_in[5];
    const float* bn1_v   = (const float*)d_in[6];
    const float* dw_w    = (const float*)d_in[7];
    const float* bn2_g   = (const float*)d_in[8];
    const float* bn2_b   = (const float*)d_in[9];
    const float* bn2_m   = (const float*)d_in[10];
    const float* bn2_v   = (const float*)d_in[11];
    const float* pw_w    = (const float*)d_in[12];
    const float* bn3_g   = (const float*)d_in[13];
    const float* bn3_b   = (const float*)d_in[14];
    const float* bn3_m   = (const float*)d_in[15];
    const float* bn3_v   = (const float*)d_in[16];
    const float* fc_w    = (const float*)d_in[17];
    const float* fc_b    = (const float*)d_in[18];

    float* out   = (float*)d_out;
    float* probs = out;                              // [1024*4]
    float* cl    = out + 4096;                       // [1]
    float* sums  = (float*)d_ws;                     // 576 floats
    int*   cnt   = (int*)((char*)d_ws + 2304);       // 4 ints
    float* feat  = (float*)((char*)d_ws + 2560);     // 1024*144 f32
    unsigned short* xrbuf = (unsigned short*)((char*)d_ws + 2560 + 589824); // bf16, 9.44 MB

    eegnet_chreduce<<<2304, 256, 0, stream>>>(x, dw_w, xrbuf, sums, cl);
    eegnet_head<<<NB, NTHR, 0, stream>>>(
        (const unsigned int*)xrbuf, y, conv1_w, bn1_g, bn1_b, bn1_m, bn1_v,
        dw_w, bn2_g, bn2_b, bn2_m, bn2_v,
        pw_w, bn3_g, bn3_b, bn3_m, bn3_v,
        fc_w, fc_b, probs, feat, sums, cnt);
    eegnet_dist<<<16, 64, 0, stream>>>(feat, y, sums, cnt, cl);
}